// Round 19
// baseline (106.559 us; speedup 1.0000x reference)
//
#include <hip/hip_runtime.h>

typedef short bf16x8 __attribute__((ext_vector_type(8)));
typedef ushort u16x4 __attribute__((ext_vector_type(4)));
typedef float f32x4 __attribute__((ext_vector_type(4)));

__device__ __forceinline__ ushort f2b(float f) {
    uint u = __builtin_bit_cast(uint, f);
    uint r = (u + 0x7fffu + ((u >> 16) & 1u)) >> 16;
    return (ushort)r;
}
__device__ __forceinline__ float b2f(ushort s) {
    uint u = ((uint)s) << 16;
    return __builtin_bit_cast(float, u);
}
__device__ __forceinline__ uint cvt_pk(float a, float b) {
    uint r;
    asm("v_cvt_pk_bf16_f32 %0, %1, %2" : "=v"(r) : "v"(a), "v"(b));
    return r;
}
// async stage of one 16KB half-tile (64 weight rows): 4 x 1KB chunks per wave
__device__ __forceinline__ void stage16k(const ushort* gsrc, ushort* ldst,
                                         int w, int lane) {
#pragma unroll
    for (int c2 = 0; c2 < 4; ++c2) {
        int off = (w * 4 + c2) * 512;   // ushort units; 1KB chunks
        __builtin_amdgcn_global_load_lds(
            (const __attribute__((address_space(1))) void*)(gsrc + off + lane * 8),
            (__attribute__((address_space(3))) void*)(ldst + off),
            16, 0, 0);
    }
}

// ---------------- prep: weights -> bf16, PRE-SWIZZLED rows (for LDS-staged B-frags) ----
__global__ __launch_bounds__(128) void prep_kernel(
        const float* __restrict__ w_q, const float* __restrict__ w_k,
        const float* __restrict__ w_v, const float* __restrict__ w_g,
        const float* __restrict__ w_o,
        ushort* __restrict__ wall, ushort* __restrict__ wo) {
    int row = blockIdx.x, col = threadIdx.x;
    int cs = col ^ ((row & 7) << 3);
    if (row < 512) {
        float val;
        if (row < 128)      val = w_q[row * 128 + col];
        else if (row < 256) val = w_k[(row - 128) * 128 + col];
        else if (row < 384) val = w_v[(row - 256) * 128 + col];
        else                val = w_g[(row - 384) * 128 + col];
        wall[row * 128 + cs] = f2b(val);
    } else {
        int r = row - 512;
        wo[r * 128 + cs] = f2b(w_o[r * 128 + col]);
    }
}

// ---------------- fused LayerNorm + pair-bias + projections, y-split ----------------
// Grid (1024, 2): y-half 0 -> q,k (+bias); y-half 1 -> v,g. Per-block serial
// stages 8 -> 4; 2048 blocks -> 5 blocks/CU (LDS-capped). LN recomputed per half.
__global__ __launch_bounds__(256, 5) void lnproj_kernel(
        const float* __restrict__ x, const float* __restrict__ w_ln,
        const float* __restrict__ b_ln, const float* __restrict__ w_b,
        const ushort* __restrict__ wall,
        ushort* __restrict__ qp, ushort* __restrict__ kp,
        ushort* __restrict__ vt, ushort* __restrict__ g,
        float* __restrict__ biasT) {
    __shared__ ushort slot0[8192];   // h-tile during LN, then odd weight stages
    __shared__ ushort slot1[8192];   // even weight stages
    int m0 = blockIdx.x * 64;
    int yhalf = blockIdx.y;
    int tid = threadIdx.x, w = tid >> 6, lane = tid & 63;
    const ushort* wsrc = wall + (size_t)yhalf * 32768;   // 2 matrices (256 rows)

    stage16k(wsrc, slot1, w, lane);   // stage 0 in flight during LN

    // ---- LN phase: wave w owns rows w*16..w*16+15, 4 lanes per row ----
    {
        int rr = lane >> 2, part = lane & 3;
        int lrow = w * 16 + rr;
        int grow = m0 + lrow;
        const float4* xr = (const float4*)(x + (size_t)grow * 128 + part * 32);
        float4 xv[8];
        float s = 0.f, sq = 0.f;
#pragma unroll
        for (int j = 0; j < 8; ++j) {
            xv[j] = xr[j];
            s += (xv[j].x + xv[j].y) + (xv[j].z + xv[j].w);
            sq += (xv[j].x * xv[j].x + xv[j].y * xv[j].y)
                + (xv[j].z * xv[j].z + xv[j].w * xv[j].w);
        }
        s += __shfl_xor(s, 1);   s += __shfl_xor(s, 2);
        sq += __shfl_xor(sq, 1); sq += __shfl_xor(sq, 2);
        float mean = s * (1.0f / 128.0f);
        float var = sq * (1.0f / 128.0f) - mean * mean;
        float rstd = rsqrtf(var + 1e-5f);
        int c0 = part * 32;
        int swr = (lrow & 7) << 3;
        float pb[4] = {0.f, 0.f, 0.f, 0.f};
#pragma unroll
        for (int j = 0; j < 8; j += 2) {
            ushort hs[8];
#pragma unroll
            for (int jj = 0; jj < 2; ++jj) {
                float4 xj = xv[j + jj];
                float4 wl = ((const float4*)(w_ln + c0))[j + jj];
                float4 bl = ((const float4*)(b_ln + c0))[j + jj];
                float h0 = (xj.x - mean) * rstd * wl.x + bl.x;
                float h1 = (xj.y - mean) * rstd * wl.y + bl.y;
                float h2 = (xj.z - mean) * rstd * wl.z + bl.z;
                float h3 = (xj.w - mean) * rstd * wl.w + bl.w;
                if (yhalf == 0) {
#pragma unroll
                    for (int hh = 0; hh < 4; ++hh) {
                        float4 wb4 = ((const float4*)(w_b + hh * 128 + c0))[j + jj];
                        pb[hh] += (h0 * wb4.x + h1 * wb4.y) + (h2 * wb4.z + h3 * wb4.w);
                    }
                }
                hs[jj * 4 + 0] = f2b(h0); hs[jj * 4 + 1] = f2b(h1);
                hs[jj * 4 + 2] = f2b(h2); hs[jj * 4 + 3] = f2b(h3);
            }
            int col = c0 + j * 4;   // 8-aligned
            *(bf16x8*)(slot0 + lrow * 128 + (col ^ swr)) = *(const bf16x8*)hs;
        }
        if (yhalf == 0) {
#pragma unroll
            for (int hh = 0; hh < 4; ++hh) {
                pb[hh] += __shfl_xor(pb[hh], 1);
                pb[hh] += __shfl_xor(pb[hh], 2);
            }
            biasT[(size_t)part * 65536 + (size_t)(grow & 255) * 256 + (grow >> 8)] =
                pb[part];
        }
    }
    __syncthreads();   // h ready; stage0 landed (vmcnt drained)

    int lo = lane & 15, hi = lane >> 4;
    int arow = w * 16 + lo;
    bf16x8 a[4];
#pragma unroll
    for (int ks = 0; ks < 4; ++ks)
        a[ks] = *(const bf16x8*)(slot0 + arow * 128 +
                                 ((ks * 32 + hi * 8) ^ ((arow & 7) << 3)));
    __syncthreads();   // all A-frag reads done; slot0 free for weight stages

    int bb = m0 >> 8;
    int pcol = (m0 & 255) + w * 16 + lo;      // m-row for swapped (q/k/g) stores
    int pbm = (m0 & 255) + w * 16 + hi * 4;   // p base for v stores
#pragma unroll 1
    for (int s = 0; s < 4; ++s) {
        if (s < 3)
            stage16k(wsrc + (size_t)(s + 1) * 8192, (s & 1) ? slot1 : slot0, w, lane);
        const ushort* cur = (s & 1) ? slot0 : slot1;   // stage s: even->slot1, odd->slot0
        int y = yhalf * 2 + (s >> 1);
#pragma unroll
        for (int ntl = 0; ntl < 4; ++ntl) {
            int nt = (s & 1) * 4 + ntl;
            int lrl = ntl * 16 + lo;
            f32x4 acc = {0.f, 0.f, 0.f, 0.f};
            if (y == 2) {
                // original orientation: lane holds 4 p-rows at fixed d
#pragma unroll
                for (int ks = 0; ks < 4; ++ks) {
                    bf16x8 bf = *(const bf16x8*)(cur + lrl * 128 +
                                                 ((ks * 32 + hi * 8) ^ ((lrl & 7) << 3)));
                    acc = __builtin_amdgcn_mfma_f32_16x16x32_bf16(a[ks], bf, acc, 0, 0, 0);
                }
                int d = nt * 16 + lo, head = d >> 5, dh = d & 31;
                size_t base = ((size_t)(bb * 4 + head)) * 8192;
                u16x4 t4;
#pragma unroll
                for (int r = 0; r < 4; ++r) t4[r] = f2b(acc[r]);
                *(u16x4*)(vt + base + dh * 256 +
                          ((((pbm >> 3) ^ (dh & 7)) << 3) + (pbm & 7))) = t4;
            } else {
                // swapped orientation: lane holds 4 consecutive features at fixed m-row
#pragma unroll
                for (int ks = 0; ks < 4; ++ks) {
                    bf16x8 bf = *(const bf16x8*)(cur + lrl * 128 +
                                                 ((ks * 32 + hi * 8) ^ ((lrl & 7) << 3)));
                    acc = __builtin_amdgcn_mfma_f32_16x16x32_bf16(bf, a[ks], acc, 0, 0, 0);
                }
                if (y == 0) {
                    int head = nt >> 1;
                    size_t base = ((size_t)(bb * 4 + head)) * 8192;
                    u16x4 t4;
#pragma unroll
                    for (int r = 0; r < 4; ++r)
                        t4[r] = f2b(acc[r] * 0.17677669529663687f);
                    *(u16x4*)(qp + base + pcol * 32 + (nt & 1) * 16 + hi * 4) = t4;
                } else if (y == 1) {
                    int head = nt >> 1;
                    size_t base = ((size_t)(bb * 4 + head)) * 8192;
                    int ch = ((nt & 1) * 2 + (hi >> 1)) ^ ((pcol >> 1) & 3);
                    u16x4 t4;
#pragma unroll
                    for (int r = 0; r < 4; ++r) t4[r] = f2b(acc[r]);
                    *(u16x4*)(kp + base + pcol * 32 + ch * 8 + (hi & 1) * 4) = t4;
                } else {
                    u16x4 t4;
#pragma unroll
                    for (int r = 0; r < 4; ++r)
                        t4[r] = f2b(1.0f / (1.0f + __expf(-acc[r])));
                    *(u16x4*)(g + (size_t)(m0 + w * 16 + lo) * 128 +
                              nt * 16 + hi * 4) = t4;
                }
            }
        }
        __syncthreads();   // drains stage s+1 loads; readers of cur done
    }
}

// ---------------- attention: K/V in LDS, dual q-tile chains (R18-exact) ------
// Swapped-QK (S^T), no-max softmax, O^T epilogue. LDS 40KB -> 4 blocks/CU.
__global__ __launch_bounds__(256, 4) void attn_kernel(
        const ushort* __restrict__ qp, const ushort* __restrict__ kp,
        const ushort* __restrict__ vt, const ushort* __restrict__ gm,
        const float* __restrict__ biasT, ushort* __restrict__ og) {
    __shared__ ushort Ks[8192];        // [p 256][d 32], 16B-chunk swizzled
    __shared__ ushort Vs[8192];        // [d 32][k 256], 16B-chunk swizzled
    __shared__ ushort P[4][1024];      // per-wave: [qt 2][512], chunk-XOR swizzled
    int blk = blockIdx.x, bh = blk & 1023, hf = blk >> 10;
    int b = bh >> 2, head = bh & 3;
    int tid = threadIdx.x, w = tid >> 6, lane = tid & 63;
    int lo = lane & 15, hi = lane >> 4;
    const ushort* kb = kp + (size_t)bh * 8192;
    const ushort* vb = vt + (size_t)bh * 8192;
    for (int idx = tid; idx < 1024; idx += 256) {
        ((float4*)Ks)[idx] = ((const float4*)kb)[idx];
        ((float4*)Vs)[idx] = ((const float4*)vb)[idx];
    }
    __syncthreads();
    ushort* pw = P[w];
    int vsw = (lo & 7);
    int kch = hi ^ ((lo >> 1) & 3);    // K chunk de-swizzle
    int pw0 = lo * 32 + (((hi >> 1) ^ (lo & 3)) << 3) + ((hi & 1) << 2);
    int pw1 = lo * 32 + (((2 | (hi >> 1)) ^ (lo & 3)) << 3) + ((hi & 1) << 2);
    int prd = lo * 32 + ((hi ^ (lo & 3)) << 3);

    int qrow0 = hf * 128 + w * 32 + lo;
    int qrow1 = qrow0 + 16;
    bf16x8 qa0 = *(const bf16x8*)(qp + (size_t)bh * 8192 + qrow0 * 32 + hi * 8);
    bf16x8 qa1 = *(const bf16x8*)(qp + (size_t)bh * 8192 + qrow1 * 32 + hi * 8);
    const float* btq0 = biasT + (size_t)head * 65536 + (size_t)(hi * 4) * 256 + qrow0;
    const float* btq1 = btq0 + 16;
    float l0 = 0.f, l1 = 0.f;
    f32x4 a00 = {0.f, 0.f, 0.f, 0.f}, a01 = {0.f, 0.f, 0.f, 0.f};
    f32x4 a10 = {0.f, 0.f, 0.f, 0.f}, a11 = {0.f, 0.f, 0.f, 0.f};
#pragma unroll
    for (int c = 0; c < 8; ++c) {
        // bias C-operands, coalesced scalar loads (16 lanes per 64B segment)
        f32x4 c00, c01, c10, c11;
#pragma unroll
        for (int r = 0; r < 4; ++r) {
            c00[r] = btq0[(c * 32 + r) * 256];
            c01[r] = btq0[(c * 32 + 16 + r) * 256];
            c10[r] = btq1[(c * 32 + r) * 256];
            c11[r] = btq1[(c * 32 + 16 + r) * 256];
        }
        // shared K fragments from LDS (feed both q-tiles)
        bf16x8 kf0 = *(const bf16x8*)(Ks + (c * 32 + lo) * 32 + kch * 8);
        bf16x8 kf1 = *(const bf16x8*)(Ks + (c * 32 + 16 + lo) * 32 + kch * 8);
        __builtin_amdgcn_s_setprio(1);
        f32x4 s00 = __builtin_amdgcn_mfma_f32_16x16x32_bf16(kf0, qa0, c00, 0, 0, 0);
        f32x4 s01 = __builtin_amdgcn_mfma_f32_16x16x32_bf16(kf1, qa0, c01, 0, 0, 0);
        f32x4 s10 = __builtin_amdgcn_mfma_f32_16x16x32_bf16(kf0, qa1, c10, 0, 0, 0);
        f32x4 s11 = __builtin_amdgcn_mfma_f32_16x16x32_bf16(kf1, qa1, c11, 0, 0, 0);
        __builtin_amdgcn_s_setprio(0);
        float e00 = __expf(s00[0]), e01 = __expf(s00[1]),
              e02 = __expf(s00[2]), e03 = __expf(s00[3]);
        float e04 = __expf(s01[0]), e05 = __expf(s01[1]),
              e06 = __expf(s01[2]), e07 = __expf(s01[3]);
        float e10 = __expf(s10[0]), e11 = __expf(s10[1]),
              e12 = __expf(s10[2]), e13 = __expf(s10[3]);
        float e14 = __expf(s11[0]), e15 = __expf(s11[1]),
              e16 = __expf(s11[2]), e17 = __expf(s11[3]);
        l0 += ((e00 + e01) + (e02 + e03)) + ((e04 + e05) + (e06 + e07));
        l1 += ((e10 + e11) + (e12 + e13)) + ((e14 + e15) + (e16 + e17));
        uint2 w00, w01, w10, w11;
        w00.x = cvt_pk(e00, e01); w00.y = cvt_pk(e02, e03);
        w01.x = cvt_pk(e04, e05); w01.y = cvt_pk(e06, e07);
        w10.x = cvt_pk(e10, e11); w10.y = cvt_pk(e12, e13);
        w11.x = cvt_pk(e14, e15); w11.y = cvt_pk(e16, e17);
        *(uint2*)(pw + pw0) = w00;
        *(uint2*)(pw + pw1) = w01;
        *(uint2*)(pw + 512 + pw0) = w10;
        *(uint2*)(pw + 512 + pw1) = w11;
        bf16x8 pf0 = *(const bf16x8*)(pw + prd);
        bf16x8 pf1 = *(const bf16x8*)(pw + 512 + prd);
        bf16x8 v0 = *(const bf16x8*)(Vs + lo * 256 + (((c * 4 + hi) ^ vsw) << 3));
        bf16x8 v1 = *(const bf16x8*)(Vs + (16 + lo) * 256 + (((c * 4 + hi) ^ vsw) << 3));
        __builtin_amdgcn_s_setprio(1);
        a00 = __builtin_amdgcn_mfma_f32_16x16x32_bf16(v0, pf0, a00, 0, 0, 0);
        a01 = __builtin_amdgcn_mfma_f32_16x16x32_bf16(v1, pf0, a01, 0, 0, 0);
        a10 = __builtin_amdgcn_mfma_f32_16x16x32_bf16(v0, pf1, a10, 0, 0, 0);
        a11 = __builtin_amdgcn_mfma_f32_16x16x32_bf16(v1, pf1, a11, 0, 0, 0);
        __builtin_amdgcn_s_setprio(0);
    }
    l0 += __shfl_xor(l0, 16);
    l0 += __shfl_xor(l0, 32);
    l1 += __shfl_xor(l1, 16);
    l1 += __shfl_xor(l1, 32);
    float rl0 = 1.0f / l0, rl1 = 1.0f / l1;
    int e0 = head * 32 + hi * 4, e1 = e0 + 16;
    int sw = (lo & 7) << 3;
    size_t mr0 = (size_t)b * 256 + qrow0;
    size_t mr1 = mr0 + 16;
    u16x4 g00 = *(const u16x4*)(gm + mr0 * 128 + e0);
    u16x4 g01 = *(const u16x4*)(gm + mr0 * 128 + e1);
    u16x4 g10 = *(const u16x4*)(gm + mr1 * 128 + e0);
    u16x4 g11 = *(const u16x4*)(gm + mr1 * 128 + e1);
    u16x4 o00, o01, o10, o11;
#pragma unroll
    for (int r = 0; r < 4; ++r) {
        o00[r] = f2b(a00[r] * rl0 * b2f(g00[r]));
        o01[r] = f2b(a01[r] * rl0 * b2f(g01[r]));
        o10[r] = f2b(a10[r] * rl1 * b2f(g10[r]));
        o11[r] = f2b(a11[r] * rl1 * b2f(g11[r]));
    }
    *(u16x4*)(og + mr0 * 128 + (e0 ^ sw)) = o00;
    *(u16x4*)(og + mr0 * 128 + (e1 ^ sw)) = o01;
    *(u16x4*)(og + mr1 * 128 + (e0 ^ sw)) = o10;
    *(u16x4*)(og + mr1 * 128 + (e1 ^ sw)) = o11;
}

// ---------------- out GEMM: out = og @ wo^T ----------------
__global__ __launch_bounds__(256) void out_kernel(
        const ushort* __restrict__ og, const ushort* __restrict__ wo,
        float* __restrict__ out) {
    __shared__ ushort wos[16384];   // 128x128 bf16 (pre-swizzled rows)
    int m0 = blockIdx.x * 64;
    for (int idx = threadIdx.x; idx < 2048; idx += 256)
        ((float4*)wos)[idx] = ((const float4*)wo)[idx];
    int tid = threadIdx.x, w = tid >> 6, lane = tid & 63;
    int lo = lane & 15, hi = lane >> 4;
    int arow = m0 + w * 16 + lo;
    bf16x8 oa[4];
#pragma unroll
    for (int ks = 0; ks < 4; ++ks)
        oa[ks] = *(const bf16x8*)(og + (size_t)arow * 128 +
                                  ((ks * 32 + hi * 8) ^ ((arow & 7) << 3)));
    __syncthreads();
    int mrow = m0 + w * 16 + hi * 4;
#pragma unroll
    for (int nt = 0; nt < 8; ++nt) {
        f32x4 acc = {0.f, 0.f, 0.f, 0.f};
        int lr = nt * 16 + lo;
#pragma unroll
        for (int ks = 0; ks < 4; ++ks) {
            bf16x8 bf = *(const bf16x8*)(wos + lr * 128 +
                                         ((ks * 32 + hi * 8) ^ ((lr & 7) << 3)));
            acc = __builtin_amdgcn_mfma_f32_16x16x32_bf16(oa[ks], bf, acc, 0, 0, 0);
        }
#pragma unroll
        for (int r = 0; r < 4; ++r)
            out[(size_t)(mrow + r) * 128 + nt * 16 + lo] = acc[r];
    }
}

extern "C" void kernel_launch(void* const* d_in, const int* in_sizes, int n_in,
                              void* d_out, int out_size, void* d_ws, size_t ws_size,
                              hipStream_t stream) {
    const float* x    = (const float*)d_in[0];
    const float* w_ln = (const float*)d_in[1];
    const float* b_ln = (const float*)d_in[2];
    const float* w_b  = (const float*)d_in[3];
    const float* w_q  = (const float*)d_in[4];
    const float* w_k  = (const float*)d_in[5];
    const float* w_v  = (const float*)d_in[6];
    const float* w_g  = (const float*)d_in[7];
    const float* w_o  = (const float*)d_in[8];
    float* out = (float*)d_out;

    char* ws = (char*)d_ws;
    const size_t MB16 = (size_t)65536 * 128 * sizeof(ushort);   // 16 MB
    ushort* qp     = (ushort*)(ws + 0 * MB16);
    ushort* kp     = (ushort*)(ws + 1 * MB16);
    ushort* vt     = (ushort*)(ws + 2 * MB16);
    ushort* g      = (ushort*)(ws + 3 * MB16);
    ushort* og     = (ushort*)(ws + 4 * MB16);
    float*  biasT  = (float*)(ws + 5 * MB16);                   // 1 MB
    ushort* wall   = (ushort*)(ws + 5 * MB16 + (size_t)65536 * 4 * 4);
    ushort* wo     = wall + 512 * 128;

    prep_kernel<<<640, 128, 0, stream>>>(w_q, w_k, w_v, w_g, w_o, wall, wo);
    lnproj_kernel<<<dim3(1024, 2), 256, 0, stream>>>(x, w_ln, b_ln, w_b, wall,
                                                     qp, kp, vt, g, biasT);
    attn_kernel<<<2048, 256, 0, stream>>>(qp, kp, vt, g, biasT, og);
    out_kernel<<<1024, 256, 0, stream>>>(og, wo, out);
}

// Round 20
// 94.905 us; speedup vs baseline: 1.1228x; 1.1228x over previous
//
#include <hip/hip_runtime.h>

typedef short bf16x8 __attribute__((ext_vector_type(8)));
typedef ushort u16x4 __attribute__((ext_vector_type(4)));
typedef float f32x4 __attribute__((ext_vector_type(4)));

__device__ __forceinline__ ushort f2b(float f) {
    uint u = __builtin_bit_cast(uint, f);
    uint r = (u + 0x7fffu + ((u >> 16) & 1u)) >> 16;
    return (ushort)r;
}
__device__ __forceinline__ float b2f(ushort s) {
    uint u = ((uint)s) << 16;
    return __builtin_bit_cast(float, u);
}
__device__ __forceinline__ uint cvt_pk(float a, float b) {
    uint r;
    asm("v_cvt_pk_bf16_f32 %0, %1, %2" : "=v"(r) : "v"(a), "v"(b));
    return r;
}
// async stage of one 16KB half-tile (64 weight rows): 4 x 1KB chunks per wave
__device__ __forceinline__ void stage16k(const ushort* gsrc, ushort* ldst,
                                         int w, int lane) {
#pragma unroll
    for (int c2 = 0; c2 < 4; ++c2) {
        int off = (w * 4 + c2) * 512;   // ushort units; 1KB chunks
        __builtin_amdgcn_global_load_lds(
            (const __attribute__((address_space(1))) void*)(gsrc + off + lane * 8),
            (__attribute__((address_space(3))) void*)(ldst + off),
            16, 0, 0);
    }
}
// barrier that does NOT drain this stage's 4 global stores:
// lgkmcnt(0) = our ds_reads done; vmcnt(4) = everything older than the 4
// newest vmem ops (i.e. this stage's prefetch loads) has landed.
__device__ __forceinline__ void stage_barrier() {
    asm volatile("s_waitcnt lgkmcnt(0) vmcnt(4)" ::: "memory");
    __builtin_amdgcn_sched_barrier(0);
    __builtin_amdgcn_s_barrier();
}

// ---------------- prep: weights -> bf16, PRE-SWIZZLED rows (for LDS-staged B-frags) ----
__global__ __launch_bounds__(128) void prep_kernel(
        const float* __restrict__ w_q, const float* __restrict__ w_k,
        const float* __restrict__ w_v, const float* __restrict__ w_g,
        const float* __restrict__ w_o,
        ushort* __restrict__ wall, ushort* __restrict__ wo) {
    int row = blockIdx.x, col = threadIdx.x;
    int cs = col ^ ((row & 7) << 3);
    if (row < 512) {
        float val;
        if (row < 128)      val = w_q[row * 128 + col];
        else if (row < 256) val = w_k[(row - 128) * 128 + col];
        else if (row < 384) val = w_v[(row - 256) * 128 + col];
        else                val = w_g[(row - 384) * 128 + col];
        wall[row * 128 + cs] = f2b(val);
    } else {
        int r = row - 512;
        wo[r * 128 + cs] = f2b(w_o[r * 128 + col]);
    }
}

// ---------------- fused LayerNorm + pair-bias + projections (R18 + counted barrier) ----
// Block = 64 rows. LN in-block, h -> slot0 (16KB). Weights in 8 async-staged
// 16KB half-tiles ping-ponging slot0/slot1. LDS 32KB. Stage barriers leave the
// stage's 4 global stores in flight (counted vmcnt).
__global__ __launch_bounds__(256, 5) void lnproj_kernel(
        const float* __restrict__ x, const float* __restrict__ w_ln,
        const float* __restrict__ b_ln, const float* __restrict__ w_b,
        const ushort* __restrict__ wall,
        ushort* __restrict__ qp, ushort* __restrict__ kp,
        ushort* __restrict__ vt, ushort* __restrict__ g,
        float* __restrict__ biasT) {
    __shared__ ushort slot0[8192];   // h-tile during LN, then odd weight stages
    __shared__ ushort slot1[8192];   // even weight stages
    int m0 = blockIdx.x * 64;
    int tid = threadIdx.x, w = tid >> 6, lane = tid & 63;

    stage16k(wall, slot1, w, lane);   // stage 0 in flight during LN

    // ---- LN + bias phase: wave w owns rows w*16..w*16+15, 4 lanes per row ----
    {
        int rr = lane >> 2, part = lane & 3;
        int lrow = w * 16 + rr;
        int grow = m0 + lrow;
        const float4* xr = (const float4*)(x + (size_t)grow * 128 + part * 32);
        float4 xv[8];
        float s = 0.f, sq = 0.f;
#pragma unroll
        for (int j = 0; j < 8; ++j) {
            xv[j] = xr[j];
            s += (xv[j].x + xv[j].y) + (xv[j].z + xv[j].w);
            sq += (xv[j].x * xv[j].x + xv[j].y * xv[j].y)
                + (xv[j].z * xv[j].z + xv[j].w * xv[j].w);
        }
        s += __shfl_xor(s, 1);   s += __shfl_xor(s, 2);
        sq += __shfl_xor(sq, 1); sq += __shfl_xor(sq, 2);
        float mean = s * (1.0f / 128.0f);
        float var = sq * (1.0f / 128.0f) - mean * mean;
        float rstd = rsqrtf(var + 1e-5f);
        int c0 = part * 32;
        int swr = (lrow & 7) << 3;
        float pb[4] = {0.f, 0.f, 0.f, 0.f};
#pragma unroll
        for (int j = 0; j < 8; j += 2) {
            ushort hs[8];
#pragma unroll
            for (int jj = 0; jj < 2; ++jj) {
                float4 xj = xv[j + jj];
                float4 wl = ((const float4*)(w_ln + c0))[j + jj];
                float4 bl = ((const float4*)(b_ln + c0))[j + jj];
                float h0 = (xj.x - mean) * rstd * wl.x + bl.x;
                float h1 = (xj.y - mean) * rstd * wl.y + bl.y;
                float h2 = (xj.z - mean) * rstd * wl.z + bl.z;
                float h3 = (xj.w - mean) * rstd * wl.w + bl.w;
#pragma unroll
                for (int hh = 0; hh < 4; ++hh) {
                    float4 wb4 = ((const float4*)(w_b + hh * 128 + c0))[j + jj];
                    pb[hh] += (h0 * wb4.x + h1 * wb4.y) + (h2 * wb4.z + h3 * wb4.w);
                }
                hs[jj * 4 + 0] = f2b(h0); hs[jj * 4 + 1] = f2b(h1);
                hs[jj * 4 + 2] = f2b(h2); hs[jj * 4 + 3] = f2b(h3);
            }
            int col = c0 + j * 4;   // 8-aligned
            *(bf16x8*)(slot0 + lrow * 128 + (col ^ swr)) = *(const bf16x8*)hs;
        }
#pragma unroll
        for (int hh = 0; hh < 4; ++hh) {
            pb[hh] += __shfl_xor(pb[hh], 1);
            pb[hh] += __shfl_xor(pb[hh], 2);
        }
        biasT[(size_t)part * 65536 + (size_t)(grow & 255) * 256 + (grow >> 8)] = pb[part];
    }
    __syncthreads();   // h ready; stage0 landed (full drain, once)

    int lo = lane & 15, hi = lane >> 4;
    int arow = w * 16 + lo;
    bf16x8 a[4];
#pragma unroll
    for (int ks = 0; ks < 4; ++ks)
        a[ks] = *(const bf16x8*)(slot0 + arow * 128 +
                                 ((ks * 32 + hi * 8) ^ ((arow & 7) << 3)));
    __syncthreads();   // all A-frag reads done; slot0 free for weight stages

    int bb = m0 >> 8;
    int pcol = (m0 & 255) + w * 16 + lo;      // m-row for swapped (q/k/g) stores
    int pbm = (m0 & 255) + w * 16 + hi * 4;   // p base for v stores
#pragma unroll 1
    for (int s = 0; s < 8; ++s) {
        if (s < 7)
            stage16k(wall + (size_t)(s + 1) * 8192, (s & 1) ? slot1 : slot0, w, lane);
        const ushort* cur = (s & 1) ? slot0 : slot1;   // stage s: even->slot1, odd->slot0
        int y = s >> 1;
#pragma unroll
        for (int ntl = 0; ntl < 4; ++ntl) {
            int nt = (s & 1) * 4 + ntl;
            int lrl = ntl * 16 + lo;
            f32x4 acc = {0.f, 0.f, 0.f, 0.f};
            if (y == 2) {
                // original orientation: lane holds 4 p-rows at fixed d
#pragma unroll
                for (int ks = 0; ks < 4; ++ks) {
                    bf16x8 bf = *(const bf16x8*)(cur + lrl * 128 +
                                                 ((ks * 32 + hi * 8) ^ ((lrl & 7) << 3)));
                    acc = __builtin_amdgcn_mfma_f32_16x16x32_bf16(a[ks], bf, acc, 0, 0, 0);
                }
                int d = nt * 16 + lo, head = d >> 5, dh = d & 31;
                size_t base = ((size_t)(bb * 4 + head)) * 8192;
                u16x4 t4;
#pragma unroll
                for (int r = 0; r < 4; ++r) t4[r] = f2b(acc[r]);
                *(u16x4*)(vt + base + dh * 256 +
                          ((((pbm >> 3) ^ (dh & 7)) << 3) + (pbm & 7))) = t4;
            } else {
                // swapped orientation: lane holds 4 consecutive features at fixed m-row
#pragma unroll
                for (int ks = 0; ks < 4; ++ks) {
                    bf16x8 bf = *(const bf16x8*)(cur + lrl * 128 +
                                                 ((ks * 32 + hi * 8) ^ ((lrl & 7) << 3)));
                    acc = __builtin_amdgcn_mfma_f32_16x16x32_bf16(bf, a[ks], acc, 0, 0, 0);
                }
                if (y == 0) {
                    int head = nt >> 1;
                    size_t base = ((size_t)(bb * 4 + head)) * 8192;
                    u16x4 t4;
#pragma unroll
                    for (int r = 0; r < 4; ++r)
                        t4[r] = f2b(acc[r] * 0.17677669529663687f);
                    *(u16x4*)(qp + base + pcol * 32 + (nt & 1) * 16 + hi * 4) = t4;
                } else if (y == 1) {
                    int head = nt >> 1;
                    size_t base = ((size_t)(bb * 4 + head)) * 8192;
                    int ch = ((nt & 1) * 2 + (hi >> 1)) ^ ((pcol >> 1) & 3);
                    u16x4 t4;
#pragma unroll
                    for (int r = 0; r < 4; ++r) t4[r] = f2b(acc[r]);
                    *(u16x4*)(kp + base + pcol * 32 + ch * 8 + (hi & 1) * 4) = t4;
                } else {
                    u16x4 t4;
#pragma unroll
                    for (int r = 0; r < 4; ++r)
                        t4[r] = f2b(1.0f / (1.0f + __expf(-acc[r])));
                    *(u16x4*)(g + (size_t)(m0 + w * 16 + lo) * 128 +
                              nt * 16 + hi * 4) = t4;
                }
            }
        }
        // counted barrier: prefetch loads guaranteed landed, stores stay in flight
        stage_barrier();
    }
}

// ---------------- attention: K/V in LDS, dual q-tile chains (R18-exact) ------
// Swapped-QK (S^T), no-max softmax, O^T epilogue. LDS 40KB -> 4 blocks/CU.
__global__ __launch_bounds__(256, 4) void attn_kernel(
        const ushort* __restrict__ qp, const ushort* __restrict__ kp,
        const ushort* __restrict__ vt, const ushort* __restrict__ gm,
        const float* __restrict__ biasT, ushort* __restrict__ og) {
    __shared__ ushort Ks[8192];        // [p 256][d 32], 16B-chunk swizzled
    __shared__ ushort Vs[8192];        // [d 32][k 256], 16B-chunk swizzled
    __shared__ ushort P[4][1024];      // per-wave: [qt 2][512], chunk-XOR swizzled
    int blk = blockIdx.x, bh = blk & 1023, hf = blk >> 10;
    int b = bh >> 2, head = bh & 3;
    int tid = threadIdx.x, w = tid >> 6, lane = tid & 63;
    int lo = lane & 15, hi = lane >> 4;
    const ushort* kb = kp + (size_t)bh * 8192;
    const ushort* vb = vt + (size_t)bh * 8192;
    for (int idx = tid; idx < 1024; idx += 256) {
        ((float4*)Ks)[idx] = ((const float4*)kb)[idx];
        ((float4*)Vs)[idx] = ((const float4*)vb)[idx];
    }
    __syncthreads();
    ushort* pw = P[w];
    int vsw = (lo & 7);
    int kch = hi ^ ((lo >> 1) & 3);    // K chunk de-swizzle
    int pw0 = lo * 32 + (((hi >> 1) ^ (lo & 3)) << 3) + ((hi & 1) << 2);
    int pw1 = lo * 32 + (((2 | (hi >> 1)) ^ (lo & 3)) << 3) + ((hi & 1) << 2);
    int prd = lo * 32 + ((hi ^ (lo & 3)) << 3);

    int qrow0 = hf * 128 + w * 32 + lo;
    int qrow1 = qrow0 + 16;
    bf16x8 qa0 = *(const bf16x8*)(qp + (size_t)bh * 8192 + qrow0 * 32 + hi * 8);
    bf16x8 qa1 = *(const bf16x8*)(qp + (size_t)bh * 8192 + qrow1 * 32 + hi * 8);
    const float* btq0 = biasT + (size_t)head * 65536 + (size_t)(hi * 4) * 256 + qrow0;
    const float* btq1 = btq0 + 16;
    float l0 = 0.f, l1 = 0.f;
    f32x4 a00 = {0.f, 0.f, 0.f, 0.f}, a01 = {0.f, 0.f, 0.f, 0.f};
    f32x4 a10 = {0.f, 0.f, 0.f, 0.f}, a11 = {0.f, 0.f, 0.f, 0.f};
#pragma unroll
    for (int c = 0; c < 8; ++c) {
        // bias C-operands, coalesced scalar loads (16 lanes per 64B segment)
        f32x4 c00, c01, c10, c11;
#pragma unroll
        for (int r = 0; r < 4; ++r) {
            c00[r] = btq0[(c * 32 + r) * 256];
            c01[r] = btq0[(c * 32 + 16 + r) * 256];
            c10[r] = btq1[(c * 32 + r) * 256];
            c11[r] = btq1[(c * 32 + 16 + r) * 256];
        }
        // shared K fragments from LDS (feed both q-tiles)
        bf16x8 kf0 = *(const bf16x8*)(Ks + (c * 32 + lo) * 32 + kch * 8);
        bf16x8 kf1 = *(const bf16x8*)(Ks + (c * 32 + 16 + lo) * 32 + kch * 8);
        __builtin_amdgcn_s_setprio(1);
        f32x4 s00 = __builtin_amdgcn_mfma_f32_16x16x32_bf16(kf0, qa0, c00, 0, 0, 0);
        f32x4 s01 = __builtin_amdgcn_mfma_f32_16x16x32_bf16(kf1, qa0, c01, 0, 0, 0);
        f32x4 s10 = __builtin_amdgcn_mfma_f32_16x16x32_bf16(kf0, qa1, c10, 0, 0, 0);
        f32x4 s11 = __builtin_amdgcn_mfma_f32_16x16x32_bf16(kf1, qa1, c11, 0, 0, 0);
        __builtin_amdgcn_s_setprio(0);
        float e00 = __expf(s00[0]), e01 = __expf(s00[1]),
              e02 = __expf(s00[2]), e03 = __expf(s00[3]);
        float e04 = __expf(s01[0]), e05 = __expf(s01[1]),
              e06 = __expf(s01[2]), e07 = __expf(s01[3]);
        float e10 = __expf(s10[0]), e11 = __expf(s10[1]),
              e12 = __expf(s10[2]), e13 = __expf(s10[3]);
        float e14 = __expf(s11[0]), e15 = __expf(s11[1]),
              e16 = __expf(s11[2]), e17 = __expf(s11[3]);
        l0 += ((e00 + e01) + (e02 + e03)) + ((e04 + e05) + (e06 + e07));
        l1 += ((e10 + e11) + (e12 + e13)) + ((e14 + e15) + (e16 + e17));
        uint2 w00, w01, w10, w11;
        w00.x = cvt_pk(e00, e01); w00.y = cvt_pk(e02, e03);
        w01.x = cvt_pk(e04, e05); w01.y = cvt_pk(e06, e07);
        w10.x = cvt_pk(e10, e11); w10.y = cvt_pk(e12, e13);
        w11.x = cvt_pk(e14, e15); w11.y = cvt_pk(e16, e17);
        *(uint2*)(pw + pw0) = w00;
        *(uint2*)(pw + pw1) = w01;
        *(uint2*)(pw + 512 + pw0) = w10;
        *(uint2*)(pw + 512 + pw1) = w11;
        bf16x8 pf0 = *(const bf16x8*)(pw + prd);
        bf16x8 pf1 = *(const bf16x8*)(pw + 512 + prd);
        bf16x8 v0 = *(const bf16x8*)(Vs + lo * 256 + (((c * 4 + hi) ^ vsw) << 3));
        bf16x8 v1 = *(const bf16x8*)(Vs + (16 + lo) * 256 + (((c * 4 + hi) ^ vsw) << 3));
        __builtin_amdgcn_s_setprio(1);
        a00 = __builtin_amdgcn_mfma_f32_16x16x32_bf16(v0, pf0, a00, 0, 0, 0);
        a01 = __builtin_amdgcn_mfma_f32_16x16x32_bf16(v1, pf0, a01, 0, 0, 0);
        a10 = __builtin_amdgcn_mfma_f32_16x16x32_bf16(v0, pf1, a10, 0, 0, 0);
        a11 = __builtin_amdgcn_mfma_f32_16x16x32_bf16(v1, pf1, a11, 0, 0, 0);
        __builtin_amdgcn_s_setprio(0);
    }
    l0 += __shfl_xor(l0, 16);
    l0 += __shfl_xor(l0, 32);
    l1 += __shfl_xor(l1, 16);
    l1 += __shfl_xor(l1, 32);
    float rl0 = 1.0f / l0, rl1 = 1.0f / l1;
    int e0 = head * 32 + hi * 4, e1 = e0 + 16;
    int sw = (lo & 7) << 3;
    size_t mr0 = (size_t)b * 256 + qrow0;
    size_t mr1 = mr0 + 16;
    u16x4 g00 = *(const u16x4*)(gm + mr0 * 128 + e0);
    u16x4 g01 = *(const u16x4*)(gm + mr0 * 128 + e1);
    u16x4 g10 = *(const u16x4*)(gm + mr1 * 128 + e0);
    u16x4 g11 = *(const u16x4*)(gm + mr1 * 128 + e1);
    u16x4 o00, o01, o10, o11;
#pragma unroll
    for (int r = 0; r < 4; ++r) {
        o00[r] = f2b(a00[r] * rl0 * b2f(g00[r]));
        o01[r] = f2b(a01[r] * rl0 * b2f(g01[r]));
        o10[r] = f2b(a10[r] * rl1 * b2f(g10[r]));
        o11[r] = f2b(a11[r] * rl1 * b2f(g11[r]));
    }
    *(u16x4*)(og + mr0 * 128 + (e0 ^ sw)) = o00;
    *(u16x4*)(og + mr0 * 128 + (e1 ^ sw)) = o01;
    *(u16x4*)(og + mr1 * 128 + (e0 ^ sw)) = o10;
    *(u16x4*)(og + mr1 * 128 + (e1 ^ sw)) = o11;
}

// ---------------- out GEMM: out = og @ wo^T ----------------
__global__ __launch_bounds__(256) void out_kernel(
        const ushort* __restrict__ og, const ushort* __restrict__ wo,
        float* __restrict__ out) {
    __shared__ ushort wos[16384];   // 128x128 bf16 (pre-swizzled rows)
    int m0 = blockIdx.x * 64;
    for (int idx = threadIdx.x; idx < 2048; idx += 256)
        ((float4*)wos)[idx] = ((const float4*)wo)[idx];
    int tid = threadIdx.x, w = tid >> 6, lane = tid & 63;
    int lo = lane & 15, hi = lane >> 4;
    int arow = m0 + w * 16 + lo;
    bf16x8 oa[4];
#pragma unroll
    for (int ks = 0; ks < 4; ++ks)
        oa[ks] = *(const bf16x8*)(og + (size_t)arow * 128 +
                                  ((ks * 32 + hi * 8) ^ ((arow & 7) << 3)));
    __syncthreads();
    int mrow = m0 + w * 16 + hi * 4;
#pragma unroll
    for (int nt = 0; nt < 8; ++nt) {
        f32x4 acc = {0.f, 0.f, 0.f, 0.f};
        int lr = nt * 16 + lo;
#pragma unroll
        for (int ks = 0; ks < 4; ++ks) {
            bf16x8 bf = *(const bf16x8*)(wos + lr * 128 +
                                         ((ks * 32 + hi * 8) ^ ((lr & 7) << 3)));
            acc = __builtin_amdgcn_mfma_f32_16x16x32_bf16(oa[ks], bf, acc, 0, 0, 0);
        }
#pragma unroll
        for (int r = 0; r < 4; ++r)
            out[(size_t)(mrow + r) * 128 + nt * 16 + lo] = acc[r];
    }
}

extern "C" void kernel_launch(void* const* d_in, const int* in_sizes, int n_in,
                              void* d_out, int out_size, void* d_ws, size_t ws_size,
                              hipStream_t stream) {
    const float* x    = (const float*)d_in[0];
    const float* w_ln = (const float*)d_in[1];
    const float* b_ln = (const float*)d_in[2];
    const float* w_b  = (const float*)d_in[3];
    const float* w_q  = (const float*)d_in[4];
    const float* w_k  = (const float*)d_in[5];
    const float* w_v  = (const float*)d_in[6];
    const float* w_g  = (const float*)d_in[7];
    const float* w_o  = (const float*)d_in[8];
    float* out = (float*)d_out;

    char* ws = (char*)d_ws;
    const size_t MB16 = (size_t)65536 * 128 * sizeof(ushort);   // 16 MB
    ushort* qp     = (ushort*)(ws + 0 * MB16);
    ushort* kp     = (ushort*)(ws + 1 * MB16);
    ushort* vt     = (ushort*)(ws + 2 * MB16);
    ushort* g      = (ushort*)(ws + 3 * MB16);
    ushort* og     = (ushort*)(ws + 4 * MB16);
    float*  biasT  = (float*)(ws + 5 * MB16);                   // 1 MB
    ushort* wall   = (ushort*)(ws + 5 * MB16 + (size_t)65536 * 4 * 4);
    ushort* wo     = wall + 512 * 128;

    prep_kernel<<<640, 128, 0, stream>>>(w_q, w_k, w_v, w_g, w_o, wall, wo);
    lnproj_kernel<<<1024, 256, 0, stream>>>(x, w_ln, b_ln, w_b, wall,
                                            qp, kp, vt, g, biasT);
    attn_kernel<<<2048, 256, 0, stream>>>(qp, kp, vt, g, biasT, og);
    out_kernel<<<1024, 256, 0, stream>>>(og, wo, out);
}